// Round 1
// baseline (969.270 us; speedup 1.0000x reference)
//
#include <hip/hip_runtime.h>
#include <hip/hip_bf16.h>

// Problem constants (derived from setup_inputs, asserted via in_sizes at launch)
// N=50000 nodes, E=1600000 edges, F0=256, F1=256, F2=128

// ---------------- CSR build ----------------

__global__ void count_kernel(const int* __restrict__ dst, int* __restrict__ cnt, int E) {
    int e = blockIdx.x * 256 + threadIdx.x;
    if (e < E) atomicAdd(&cnt[dst[e]], 1);
}

// single-block inclusive scan: offs[0]=0, offs[i+1]=sum(cnt[0..i])
__global__ void scan_kernel(const int* __restrict__ cnt, int* __restrict__ offs, int n) {
    __shared__ int s[256];
    int carry = 0;
    if (threadIdx.x == 0) offs[0] = 0;
    for (int base = 0; base < n; base += 1024) {
        int i0 = base + threadIdx.x * 4;
        int v[4];
#pragma unroll
        for (int j = 0; j < 4; ++j) v[j] = (i0 + j < n) ? cnt[i0 + j] : 0;
        int lsum = v[0] + v[1] + v[2] + v[3];
        s[threadIdx.x] = lsum;
        __syncthreads();
        for (int off = 1; off < 256; off <<= 1) {
            int t = (threadIdx.x >= off) ? s[threadIdx.x - off] : 0;
            __syncthreads();
            s[threadIdx.x] += t;
            __syncthreads();
        }
        int run = s[threadIdx.x] - lsum + carry;  // exclusive prefix for this thread
#pragma unroll
        for (int j = 0; j < 4; ++j) {
            run += v[j];
            if (i0 + j < n) offs[i0 + j + 1] = run;
        }
        carry += s[255];
        __syncthreads();
    }
}

__global__ void dinv_cursor_kernel(const int* __restrict__ cnt, const int* __restrict__ offs,
                                   float* __restrict__ dinv, int* __restrict__ cursor, int n) {
    int i = blockIdx.x * 256 + threadIdx.x;
    if (i < n) {
        dinv[i] = rsqrtf((float)(cnt[i] + 1));  // +1 self loop
        cursor[i] = offs[i];
    }
}

__global__ void place_kernel(const int* __restrict__ src, const int* __restrict__ dst,
                             int* __restrict__ cursor, int* __restrict__ ssrc, int E) {
    int e = blockIdx.x * 256 + threadIdx.x;
    if (e < E) {
        int p = atomicAdd(&cursor[dst[e]], 1);
        ssrc[p] = src[e];
    }
}

// ---------------- fp32 GEMM: C[M,N] = A[M,K] @ B[K,N]; BM=BN=64, BK=16, 4x4/thread ----------------

__global__ __launch_bounds__(256) void gemm_kernel(const float* __restrict__ A,
                                                   const float* __restrict__ B,
                                                   float* __restrict__ C,
                                                   int M, int K, int N) {
    __shared__ float As[16][64];
    __shared__ float Bs[16][64];
    int tid = threadIdx.x;
    int tx = tid & 15, ty = tid >> 4;
    int r0 = blockIdx.x * 64, c0 = blockIdx.y * 64;
    float acc[4][4] = {};
    int lm = tid >> 2;         // A-load: row within tile (0..63)
    int lk = (tid & 3) * 4;    // A-load: k offset (0,4,8,12)
    int bk = tid >> 4;         // B-load: k row (0..15)
    int bn0 = (tid & 15) * 4;  // B-load: col offset
    for (int k0 = 0; k0 < K; k0 += 16) {
        int ar = r0 + lm;
        float4 a4 = (ar < M) ? *(const float4*)&A[(size_t)ar * K + k0 + lk]
                             : make_float4(0.f, 0.f, 0.f, 0.f);
        As[lk + 0][lm] = a4.x; As[lk + 1][lm] = a4.y;
        As[lk + 2][lm] = a4.z; As[lk + 3][lm] = a4.w;
        *(float4*)&Bs[bk][bn0] = *(const float4*)&B[(size_t)(k0 + bk) * N + c0 + bn0];
        __syncthreads();
#pragma unroll
        for (int kk = 0; kk < 16; ++kk) {
            float4 a = *(const float4*)&As[kk][ty * 4];
            float4 b = *(const float4*)&Bs[kk][tx * 4];
            float av[4] = {a.x, a.y, a.z, a.w};
            float bv[4] = {b.x, b.y, b.z, b.w};
#pragma unroll
            for (int i = 0; i < 4; ++i)
#pragma unroll
                for (int j = 0; j < 4; ++j) acc[i][j] = fmaf(av[i], bv[j], acc[i][j]);
        }
        __syncthreads();
    }
#pragma unroll
    for (int i = 0; i < 4; ++i) {
        int r = r0 + ty * 4 + i;
        if (r < M)
            *(float4*)&C[(size_t)r * N + c0 + tx * 4] =
                make_float4(acc[i][0], acc[i][1], acc[i][2], acc[i][3]);
    }
}

// ---------------- per-node aggregation (CSR, no atomics) ----------------
// out[n] = dinv[n] * (sum_{e in edges(dst=n)} dinv[src]*h[src] + dinv[n]*h[n]) + bias

template <int C, bool RELU>
__global__ void agg_kernel(const float* __restrict__ h, const float* __restrict__ dinv,
                           const int* __restrict__ offs, const int* __restrict__ ssrc,
                           const float* __restrict__ bias, float* __restrict__ out) {
    int n = blockIdx.x;
    int t = threadIdx.x;  // one column per thread, blockDim.x == C
    float di = dinv[n];
    float acc = di * h[(size_t)n * C + t];  // self loop (scaled by di again below)
    int e0 = offs[n], e1 = offs[n + 1];
    for (int e = e0; e < e1; ++e) {
        int s = ssrc[e];
        acc += dinv[s] * h[(size_t)s * C + t];
    }
    float v = acc * di + bias[t];
    if (RELU) v = fmaxf(v, 0.f);
    out[(size_t)n * C + t] = v;
}

// ---------------- launch ----------------

extern "C" void kernel_launch(void* const* d_in, const int* in_sizes, int n_in,
                              void* d_out, int out_size, void* d_ws, size_t ws_size,
                              hipStream_t stream) {
    const float* x  = (const float*)d_in[0];   // [N,256]
    const int*   ei = (const int*)d_in[1];     // [2,E]
    const float* W1 = (const float*)d_in[2];   // [256,256]
    const float* b1 = (const float*)d_in[3];   // [256]
    const float* W2 = (const float*)d_in[4];   // [256,128]
    const float* b2 = (const float*)d_in[5];   // [128]
    float* out = (float*)d_out;

    const int F0 = 256, F1 = 256, F2 = 128;
    const int N = in_sizes[0] / F0;            // 50000
    const int E = in_sizes[1] / 2;             // 1600000
    const int* src = ei;
    const int* dst = ei + E;

    // workspace carve-up (256B aligned)
    char* ws = (char*)d_ws;
    size_t off = 0;
    auto alloc = [&](size_t bytes) {
        char* p = ws + off;
        off += (bytes + 255) & ~(size_t)255;
        return p;
    };
    int*   cnt    = (int*)alloc((size_t)N * 4);
    int*   offs   = (int*)alloc((size_t)(N + 1) * 4);
    int*   cursor = (int*)alloc((size_t)N * 4);
    float* dinv   = (float*)alloc((size_t)N * 4);
    int*   ssrc   = (int*)alloc((size_t)E * 4);
    float* h1     = (float*)alloc((size_t)N * F1 * 4);   // x@W1 ; reused as h2 later
    float* h1a    = (float*)alloc((size_t)N * F1 * 4);   // relu(agg(h1))
    float* h2     = h1;                                   // h1 dead after agg1
    (void)ws_size; (void)n_in; (void)out_size;

    // 1. CSR build
    hipMemsetAsync(cnt, 0, (size_t)N * 4, stream);
    count_kernel<<<(E + 255) / 256, 256, 0, stream>>>(dst, cnt, E);
    scan_kernel<<<1, 256, 0, stream>>>(cnt, offs, N);
    dinv_cursor_kernel<<<(N + 255) / 256, 256, 0, stream>>>(cnt, offs, dinv, cursor, N);
    place_kernel<<<(E + 255) / 256, 256, 0, stream>>>(src, dst, cursor, ssrc, E);

    // 2. layer 1: h1 = x @ W1 ; h1a = relu(agg(h1) + b1)
    {
        dim3 grid((N + 63) / 64, F1 / 64);
        gemm_kernel<<<grid, 256, 0, stream>>>(x, W1, h1, N, F0, F1);
    }
    agg_kernel<F1, true><<<N, F1, 0, stream>>>(h1, dinv, offs, ssrc, b1, h1a);

    // 3. layer 2: h2 = h1a @ W2 ; out = agg(h2) + b2
    {
        dim3 grid((N + 63) / 64, F2 / 64);
        gemm_kernel<<<grid, 256, 0, stream>>>(h1a, W2, h2, N, F1, F2);
    }
    agg_kernel<F2, false><<<N, F2, 0, stream>>>(h2, dinv, offs, ssrc, b2, out);
}

// Round 2
// 693.137 us; speedup vs baseline: 1.3984x; 1.3984x over previous
//
#include <hip/hip_runtime.h>
#include <hip/hip_bf16.h>

// N=50000 nodes, E=1600000 edges, F0=256, F1=256, F2=128
// Pipeline: h1=x@W1 (bf16 out) -> h1a=relu(agg(h1))+b1 (fp32)
//           h2=h1a@W2 (bf16 out) -> out=agg(h2)+b2 (fp32)
// h1/h2 are ONLY read by the gather-heavy agg kernels -> store them bf16
// to halve the random-gather traffic (the round-1 bottleneck: 794MB L2-miss
// fetch, 317us, VALUBusy 7.5% => byte-throughput-bound, not latency-bound).

__device__ inline unsigned short f2bf(float f) {
    unsigned u = __float_as_uint(f);
    u += 0x7FFFu + ((u >> 16) & 1u);  // round-to-nearest-even
    return (unsigned short)(u >> 16);
}

// ---------------- CSR build ----------------

__global__ void count_kernel(const int* __restrict__ dst, int* __restrict__ cnt, int E) {
    int e = blockIdx.x * 256 + threadIdx.x;
    if (e < E) atomicAdd(&cnt[dst[e]], 1);
}

__global__ void scan_kernel(const int* __restrict__ cnt, int* __restrict__ offs, int n) {
    __shared__ int s[256];
    int carry = 0;
    if (threadIdx.x == 0) offs[0] = 0;
    for (int base = 0; base < n; base += 1024) {
        int i0 = base + threadIdx.x * 4;
        int v[4];
#pragma unroll
        for (int j = 0; j < 4; ++j) v[j] = (i0 + j < n) ? cnt[i0 + j] : 0;
        int lsum = v[0] + v[1] + v[2] + v[3];
        s[threadIdx.x] = lsum;
        __syncthreads();
        for (int off = 1; off < 256; off <<= 1) {
            int t = (threadIdx.x >= off) ? s[threadIdx.x - off] : 0;
            __syncthreads();
            s[threadIdx.x] += t;
            __syncthreads();
        }
        int run = s[threadIdx.x] - lsum + carry;
#pragma unroll
        for (int j = 0; j < 4; ++j) {
            run += v[j];
            if (i0 + j < n) offs[i0 + j + 1] = run;
        }
        carry += s[255];
        __syncthreads();
    }
}

__global__ void dinv_cursor_kernel(const int* __restrict__ cnt, const int* __restrict__ offs,
                                   float* __restrict__ dinv, int* __restrict__ cursor, int n) {
    int i = blockIdx.x * 256 + threadIdx.x;
    if (i < n) {
        dinv[i] = rsqrtf((float)(cnt[i] + 1));
        cursor[i] = offs[i];
    }
}

__global__ void place_kernel(const int* __restrict__ src, const int* __restrict__ dst,
                             int* __restrict__ cursor, int* __restrict__ ssrc, int E) {
    int e = blockIdx.x * 256 + threadIdx.x;
    if (e < E) {
        int p = atomicAdd(&cursor[dst[e]], 1);
        ssrc[p] = src[e];
    }
}

// ---------------- fp32 GEMM, bf16 output: C[M,N] = A[M,K] @ B[K,N] ----------------
// BM=BN=64, BK=16, 4x4 per thread, 256 threads.

__global__ __launch_bounds__(256) void gemm_bf16out_kernel(const float* __restrict__ A,
                                                           const float* __restrict__ B,
                                                           unsigned short* __restrict__ C,
                                                           int M, int K, int N) {
    __shared__ float As[16][64];
    __shared__ float Bs[16][64];
    int tid = threadIdx.x;
    int tx = tid & 15, ty = tid >> 4;
    int r0 = blockIdx.x * 64, c0 = blockIdx.y * 64;
    float acc[4][4] = {};
    int lm = tid >> 2;
    int lk = (tid & 3) * 4;
    int bk = tid >> 4;
    int bn0 = (tid & 15) * 4;
    for (int k0 = 0; k0 < K; k0 += 16) {
        int ar = r0 + lm;
        float4 a4 = (ar < M) ? *(const float4*)&A[(size_t)ar * K + k0 + lk]
                             : make_float4(0.f, 0.f, 0.f, 0.f);
        As[lk + 0][lm] = a4.x; As[lk + 1][lm] = a4.y;
        As[lk + 2][lm] = a4.z; As[lk + 3][lm] = a4.w;
        *(float4*)&Bs[bk][bn0] = *(const float4*)&B[(size_t)(k0 + bk) * N + c0 + bn0];
        __syncthreads();
#pragma unroll
        for (int kk = 0; kk < 16; ++kk) {
            float4 a = *(const float4*)&As[kk][ty * 4];
            float4 b = *(const float4*)&Bs[kk][tx * 4];
            float av[4] = {a.x, a.y, a.z, a.w};
            float bv[4] = {b.x, b.y, b.z, b.w};
#pragma unroll
            for (int i = 0; i < 4; ++i)
#pragma unroll
                for (int j = 0; j < 4; ++j) acc[i][j] = fmaf(av[i], bv[j], acc[i][j]);
        }
        __syncthreads();
    }
#pragma unroll
    for (int i = 0; i < 4; ++i) {
        int r = r0 + ty * 4 + i;
        if (r < M) {
            uint2 p;
            p.x = (unsigned)f2bf(acc[i][0]) | ((unsigned)f2bf(acc[i][1]) << 16);
            p.y = (unsigned)f2bf(acc[i][2]) | ((unsigned)f2bf(acc[i][3]) << 16);
            *(uint2*)&C[(size_t)r * N + c0 + tx * 4] = p;
        }
    }
}

// ---------------- aggregation: one wave per node, bf16 gather, fp32 out ----------------
// out[n] = dinv[n] * (dinv[n]*h[n] + sum_e dinv[src_e]*h[src_e]) + bias ; optional ReLU
// F=256: lane owns 4 cols (ushort4 8B load); F=128: lane owns 2 cols (ushort2 4B).

template <int F, bool RELU>
__global__ __launch_bounds__(256) void agg_kernel(const unsigned short* __restrict__ h,
                                                  const float* __restrict__ dinv,
                                                  const int* __restrict__ offs,
                                                  const int* __restrict__ ssrc,
                                                  const float* __restrict__ bias,
                                                  float* __restrict__ out, int N) {
    constexpr int V = F / 64;  // cols per lane (4 or 2)
    int n = blockIdx.x * 4 + (threadIdx.x >> 6);
    if (n >= N) return;
    int lane = threadIdx.x & 63;
    int c = lane * V;
    float di = dinv[n];
    float acc[V];

    auto loadrow = [&](int row, float w, float* a, bool init) {
        const unsigned short* p = h + (size_t)row * F + c;
        if constexpr (V == 4) {
            uint2 q = *(const uint2*)p;
            float f0 = __uint_as_float(q.x << 16);
            float f1 = __uint_as_float(q.x & 0xFFFF0000u);
            float f2 = __uint_as_float(q.y << 16);
            float f3 = __uint_as_float(q.y & 0xFFFF0000u);
            if (init) { a[0] = w * f0; a[1] = w * f1; a[2] = w * f2; a[3] = w * f3; }
            else { a[0] = fmaf(w, f0, a[0]); a[1] = fmaf(w, f1, a[1]);
                   a[2] = fmaf(w, f2, a[2]); a[3] = fmaf(w, f3, a[3]); }
        } else {
            unsigned q = *(const unsigned*)p;
            float f0 = __uint_as_float(q << 16);
            float f1 = __uint_as_float(q & 0xFFFF0000u);
            if (init) { a[0] = w * f0; a[1] = w * f1; }
            else { a[0] = fmaf(w, f0, a[0]); a[1] = fmaf(w, f1, a[1]); }
        }
    };

    loadrow(n, di, acc, true);  // self loop (gets second di factor at the end)

    int e = offs[n], e1 = offs[n + 1];
    for (; e + 4 <= e1; e += 4) {
        int s0 = ssrc[e + 0], s1 = ssrc[e + 1], s2 = ssrc[e + 2], s3 = ssrc[e + 3];
        float d0 = dinv[s0], d1 = dinv[s1], d2 = dinv[s2], d3 = dinv[s3];
        loadrow(s0, d0, acc, false);
        loadrow(s1, d1, acc, false);
        loadrow(s2, d2, acc, false);
        loadrow(s3, d3, acc, false);
    }
    for (; e < e1; ++e) {
        int s = ssrc[e];
        loadrow(s, dinv[s], acc, false);
    }

#pragma unroll
    for (int v = 0; v < V; ++v) {
        float r = fmaf(acc[v], di, bias[c + v]);
        if (RELU) r = fmaxf(r, 0.f);
        out[(size_t)n * F + c + v] = r;
    }
}

// ---------------- launch ----------------

extern "C" void kernel_launch(void* const* d_in, const int* in_sizes, int n_in,
                              void* d_out, int out_size, void* d_ws, size_t ws_size,
                              hipStream_t stream) {
    const float* x  = (const float*)d_in[0];
    const int*   ei = (const int*)d_in[1];
    const float* W1 = (const float*)d_in[2];
    const float* b1 = (const float*)d_in[3];
    const float* W2 = (const float*)d_in[4];
    const float* b2 = (const float*)d_in[5];
    float* out = (float*)d_out;

    const int F0 = 256, F1 = 256, F2 = 128;
    const int N = in_sizes[0] / F0;   // 50000
    const int E = in_sizes[1] / 2;    // 1600000
    const int* src = ei;
    const int* dst = ei + E;

    char* ws = (char*)d_ws;
    size_t off = 0;
    auto alloc = [&](size_t bytes) {
        char* p = ws + off;
        off += (bytes + 255) & ~(size_t)255;
        return p;
    };
    int*            cnt    = (int*)alloc((size_t)N * 4);
    int*            offs   = (int*)alloc((size_t)(N + 1) * 4);
    int*            cursor = (int*)alloc((size_t)N * 4);
    float*          dinv   = (float*)alloc((size_t)N * 4);
    int*            ssrc   = (int*)alloc((size_t)E * 4);
    unsigned short* h1     = (unsigned short*)alloc((size_t)N * F1 * 2);  // bf16
    float*          h1a    = (float*)alloc((size_t)N * F1 * 4);           // fp32
    unsigned short* h2     = (unsigned short*)alloc((size_t)N * F2 * 2);  // bf16
    (void)ws_size; (void)n_in; (void)out_size;

    // CSR build
    hipMemsetAsync(cnt, 0, (size_t)N * 4, stream);
    count_kernel<<<(E + 255) / 256, 256, 0, stream>>>(dst, cnt, E);
    scan_kernel<<<1, 256, 0, stream>>>(cnt, offs, N);
    dinv_cursor_kernel<<<(N + 255) / 256, 256, 0, stream>>>(cnt, offs, dinv, cursor, N);
    place_kernel<<<(E + 255) / 256, 256, 0, stream>>>(src, dst, cursor, ssrc, E);

    // layer 1
    {
        dim3 grid((N + 63) / 64, F1 / 64);
        gemm_bf16out_kernel<<<grid, 256, 0, stream>>>(x, W1, h1, N, F0, F1);
    }
    agg_kernel<256, true><<<(N + 3) / 4, 256, 0, stream>>>(h1, dinv, offs, ssrc, b1, h1a, N);

    // layer 2
    {
        dim3 grid((N + 63) / 64, F2 / 64);
        gemm_bf16out_kernel<<<grid, 256, 0, stream>>>(h1a, W2, h2, N, F1, F2);
    }
    agg_kernel<128, false><<<(N + 3) / 4, 256, 0, stream>>>(h2, dinv, offs, ssrc, b2, out, N);
}

// Round 3
// 648.259 us; speedup vs baseline: 1.4952x; 1.0692x over previous
//
#include <hip/hip_runtime.h>
#include <hip/hip_bf16.h>

// N=50000, E=1600000, F0=256, F1=256, F2=128
// R2 bottleneck: place_kernel WRITE_SIZE=101MB for a 6.4MB array (16x write
// amplification: each 4B scatter-write dirties a 64B line touched by waves on
// all 8 XCDs; non-coherent per-XCD L2s flush partial lines through HBM).
// R3 fix: XCD-local CSR build. Blocks in group g=blockIdx%8 sweep the whole
// edge list but only place edges with dst in node-range g, so each slice of
// ssrc/cnt/cursor is owned by one XCD's L2 and evicted once.

__device__ inline unsigned short f2bf(float f) {
    unsigned u = __float_as_uint(f);
    u += 0x7FFFu + ((u >> 16) & 1u);  // RNE
    return (unsigned short)(u >> 16);
}

// ---------------- CSR build (XCD-partitioned) ----------------

#define XCDS 8

__global__ __launch_bounds__(256) void count_kernel_x(const int* __restrict__ dst,
                                                      int* __restrict__ cnt, int E, int ng) {
    int g = blockIdx.x & (XCDS - 1);
    int lo = g * ng, hi = lo + ng;
    int bpg = gridDim.x >> 3;           // blocks per group
    int bid = blockIdx.x >> 3;
    int stride = bpg * 256;
    for (int e = bid * 256 + threadIdx.x; e < E; e += stride) {
        int d = dst[e];
        if (d >= lo && d < hi) atomicAdd(&cnt[d], 1);
    }
}

__global__ __launch_bounds__(256) void place_kernel_x(const int* __restrict__ src,
                                                      const int* __restrict__ dst,
                                                      int* __restrict__ cursor,
                                                      int* __restrict__ ssrc, int E, int ng) {
    int g = blockIdx.x & (XCDS - 1);
    int lo = g * ng, hi = lo + ng;
    int bpg = gridDim.x >> 3;
    int bid = blockIdx.x >> 3;
    int stride = bpg * 256;
    for (int e = bid * 256 + threadIdx.x; e < E; e += stride) {
        int d = dst[e];
        if (d >= lo && d < hi) {
            int p = atomicAdd(&cursor[d], 1);
            ssrc[p] = src[e];
        }
    }
}

__global__ void scan_kernel(const int* __restrict__ cnt, int* __restrict__ offs, int n) {
    __shared__ int s[256];
    int carry = 0;
    if (threadIdx.x == 0) offs[0] = 0;
    for (int base = 0; base < n; base += 1024) {
        int i0 = base + threadIdx.x * 4;
        int v[4];
#pragma unroll
        for (int j = 0; j < 4; ++j) v[j] = (i0 + j < n) ? cnt[i0 + j] : 0;
        int lsum = v[0] + v[1] + v[2] + v[3];
        s[threadIdx.x] = lsum;
        __syncthreads();
        for (int off = 1; off < 256; off <<= 1) {
            int t = (threadIdx.x >= off) ? s[threadIdx.x - off] : 0;
            __syncthreads();
            s[threadIdx.x] += t;
            __syncthreads();
        }
        int run = s[threadIdx.x] - lsum + carry;
#pragma unroll
        for (int j = 0; j < 4; ++j) {
            run += v[j];
            if (i0 + j < n) offs[i0 + j + 1] = run;
        }
        carry += s[255];
        __syncthreads();
    }
}

__global__ void dinv_cursor_kernel(const int* __restrict__ cnt, const int* __restrict__ offs,
                                   float* __restrict__ dinv, int* __restrict__ cursor, int n) {
    int i = blockIdx.x * 256 + threadIdx.x;
    if (i < n) {
        dinv[i] = rsqrtf((float)(cnt[i] + 1));
        cursor[i] = offs[i];
    }
}

// ---------------- fp32 GEMM, bf16 output ----------------

__global__ __launch_bounds__(256) void gemm_bf16out_kernel(const float* __restrict__ A,
                                                           const float* __restrict__ B,
                                                           unsigned short* __restrict__ C,
                                                           int M, int K, int N) {
    __shared__ float As[16][64];
    __shared__ float Bs[16][64];
    int tid = threadIdx.x;
    int tx = tid & 15, ty = tid >> 4;
    int r0 = blockIdx.x * 64, c0 = blockIdx.y * 64;
    float acc[4][4] = {};
    int lm = tid >> 2;
    int lk = (tid & 3) * 4;
    int bk = tid >> 4;
    int bn0 = (tid & 15) * 4;
    for (int k0 = 0; k0 < K; k0 += 16) {
        int ar = r0 + lm;
        float4 a4 = (ar < M) ? *(const float4*)&A[(size_t)ar * K + k0 + lk]
                             : make_float4(0.f, 0.f, 0.f, 0.f);
        As[lk + 0][lm] = a4.x; As[lk + 1][lm] = a4.y;
        As[lk + 2][lm] = a4.z; As[lk + 3][lm] = a4.w;
        *(float4*)&Bs[bk][bn0] = *(const float4*)&B[(size_t)(k0 + bk) * N + c0 + bn0];
        __syncthreads();
#pragma unroll
        for (int kk = 0; kk < 16; ++kk) {
            float4 a = *(const float4*)&As[kk][ty * 4];
            float4 b = *(const float4*)&Bs[kk][tx * 4];
            float av[4] = {a.x, a.y, a.z, a.w};
            float bv[4] = {b.x, b.y, b.z, b.w};
#pragma unroll
            for (int i = 0; i < 4; ++i)
#pragma unroll
                for (int j = 0; j < 4; ++j) acc[i][j] = fmaf(av[i], bv[j], acc[i][j]);
        }
        __syncthreads();
    }
#pragma unroll
    for (int i = 0; i < 4; ++i) {
        int r = r0 + ty * 4 + i;
        if (r < M) {
            uint2 p;
            p.x = (unsigned)f2bf(acc[i][0]) | ((unsigned)f2bf(acc[i][1]) << 16);
            p.y = (unsigned)f2bf(acc[i][2]) | ((unsigned)f2bf(acc[i][3]) << 16);
            *(uint2*)&C[(size_t)r * N + c0 + tx * 4] = p;
        }
    }
}

// ---------------- aggregation: one wave per node, bf16 gather, fp32 out ----------------

template <int F, bool RELU>
__global__ __launch_bounds__(256) void agg_kernel(const unsigned short* __restrict__ h,
                                                  const float* __restrict__ dinv,
                                                  const int* __restrict__ offs,
                                                  const int* __restrict__ ssrc,
                                                  const float* __restrict__ bias,
                                                  float* __restrict__ out, int N) {
    constexpr int V = F / 64;
    int n = blockIdx.x * 4 + (threadIdx.x >> 6);
    if (n >= N) return;
    int lane = threadIdx.x & 63;
    int c = lane * V;
    float di = dinv[n];
    float acc[V];

    auto loadrow = [&](int row, float w, float* a, bool init) {
        const unsigned short* p = h + (size_t)row * F + c;
        if constexpr (V == 4) {
            uint2 q = *(const uint2*)p;
            float f0 = __uint_as_float(q.x << 16);
            float f1 = __uint_as_float(q.x & 0xFFFF0000u);
            float f2 = __uint_as_float(q.y << 16);
            float f3 = __uint_as_float(q.y & 0xFFFF0000u);
            if (init) { a[0] = w * f0; a[1] = w * f1; a[2] = w * f2; a[3] = w * f3; }
            else { a[0] = fmaf(w, f0, a[0]); a[1] = fmaf(w, f1, a[1]);
                   a[2] = fmaf(w, f2, a[2]); a[3] = fmaf(w, f3, a[3]); }
        } else {
            unsigned q = *(const unsigned*)p;
            float f0 = __uint_as_float(q << 16);
            float f1 = __uint_as_float(q & 0xFFFF0000u);
            if (init) { a[0] = w * f0; a[1] = w * f1; }
            else { a[0] = fmaf(w, f0, a[0]); a[1] = fmaf(w, f1, a[1]); }
        }
    };

    loadrow(n, di, acc, true);

    int e = offs[n], e1 = offs[n + 1];
    for (; e + 4 <= e1; e += 4) {
        int s0 = ssrc[e + 0], s1 = ssrc[e + 1], s2 = ssrc[e + 2], s3 = ssrc[e + 3];
        float d0 = dinv[s0], d1 = dinv[s1], d2 = dinv[s2], d3 = dinv[s3];
        loadrow(s0, d0, acc, false);
        loadrow(s1, d1, acc, false);
        loadrow(s2, d2, acc, false);
        loadrow(s3, d3, acc, false);
    }
    for (; e < e1; ++e) {
        int s = ssrc[e];
        loadrow(s, dinv[s], acc, false);
    }

#pragma unroll
    for (int v = 0; v < V; ++v) {
        float r = fmaf(acc[v], di, bias[c + v]);
        if (RELU) r = fmaxf(r, 0.f);
        out[(size_t)n * F + c + v] = r;
    }
}

// ---------------- launch ----------------

extern "C" void kernel_launch(void* const* d_in, const int* in_sizes, int n_in,
                              void* d_out, int out_size, void* d_ws, size_t ws_size,
                              hipStream_t stream) {
    const float* x  = (const float*)d_in[0];
    const int*   ei = (const int*)d_in[1];
    const float* W1 = (const float*)d_in[2];
    const float* b1 = (const float*)d_in[3];
    const float* W2 = (const float*)d_in[4];
    const float* b2 = (const float*)d_in[5];
    float* out = (float*)d_out;

    const int F0 = 256, F1 = 256, F2 = 128;
    const int N = in_sizes[0] / F0;   // 50000
    const int E = in_sizes[1] / 2;    // 1600000
    const int* src = ei;
    const int* dst = ei + E;
    const int ng = (N + XCDS - 1) / XCDS;  // 6250 nodes per XCD group

    char* ws = (char*)d_ws;
    size_t off = 0;
    auto alloc = [&](size_t bytes) {
        char* p = ws + off;
        off += (bytes + 255) & ~(size_t)255;
        return p;
    };
    int*            cnt    = (int*)alloc((size_t)N * 4);
    int*            offs   = (int*)alloc((size_t)(N + 1) * 4);
    int*            cursor = (int*)alloc((size_t)N * 4);
    float*          dinv   = (float*)alloc((size_t)N * 4);
    int*            ssrc   = (int*)alloc((size_t)E * 4);
    unsigned short* h1     = (unsigned short*)alloc((size_t)N * F1 * 2);
    float*          h1a    = (float*)alloc((size_t)N * F1 * 4);
    unsigned short* h2     = (unsigned short*)alloc((size_t)N * F2 * 2);
    (void)ws_size; (void)n_in; (void)out_size;

    // CSR build, XCD-partitioned (2048 blocks = 256 per group)
    hipMemsetAsync(cnt, 0, (size_t)N * 4, stream);
    count_kernel_x<<<2048, 256, 0, stream>>>(dst, cnt, E, ng);
    scan_kernel<<<1, 256, 0, stream>>>(cnt, offs, N);
    dinv_cursor_kernel<<<(N + 255) / 256, 256, 0, stream>>>(cnt, offs, dinv, cursor, N);
    place_kernel_x<<<2048, 256, 0, stream>>>(src, dst, cursor, ssrc, E, ng);

    // layer 1
    {
        dim3 grid((N + 63) / 64, F1 / 64);
        gemm_bf16out_kernel<<<grid, 256, 0, stream>>>(x, W1, h1, N, F0, F1);
    }
    agg_kernel<256, true><<<(N + 3) / 4, 256, 0, stream>>>(h1, dinv, offs, ssrc, b1, h1a, N);

    // layer 2
    {
        dim3 grid((N + 63) / 64, F2 / 64);
        gemm_bf16out_kernel<<<grid, 256, 0, stream>>>(h1a, W2, h2, N, F1, F2);
    }
    agg_kernel<128, false><<<(N + 3) / 4, 256, 0, stream>>>(h2, dinv, offs, ssrc, b2, out, N);
}

// Round 4
// 536.982 us; speedup vs baseline: 1.8050x; 1.2072x over previous
//
#include <hip/hip_runtime.h>
#include <hip/hip_bf16.h>

// N=50000, E=1600000, F0=256, F1=256, F2=128
// R3 bottleneck: fp32 vector GEMM1 (113us, VALUBusy 69%, MfmaUtil 0).
// R4: bf16 MFMA GEMMs (16x16x32), x cast to bf16 once, W1/W2 transposed+cast
// so B-fragments load contiguously; agg1 emits bf16 so GEMM2 reads bf16 A.

typedef __bf16 bf16x8 __attribute__((ext_vector_type(8)));
typedef float f32x4 __attribute__((ext_vector_type(4)));

__device__ inline unsigned short f2bf(float f) {
    unsigned u = __float_as_uint(f);
    u += 0x7FFFu + ((u >> 16) & 1u);  // RNE
    return (unsigned short)(u >> 16);
}
__device__ inline void storev(float* p, float v) { *p = v; }
__device__ inline void storev(unsigned short* p, float v) { *p = f2bf(v); }

// ---------------- CSR build (XCD-partitioned, from R3) ----------------

#define XCDS 8

__global__ __launch_bounds__(256) void count_kernel_x(const int* __restrict__ dst,
                                                      int* __restrict__ cnt, int E, int ng) {
    int g = blockIdx.x & (XCDS - 1);
    int lo = g * ng, hi = lo + ng;
    int bid = blockIdx.x >> 3;
    int stride = (gridDim.x >> 3) * 256;
    for (int e = bid * 256 + threadIdx.x; e < E; e += stride) {
        int d = dst[e];
        if (d >= lo && d < hi) atomicAdd(&cnt[d], 1);
    }
}

__global__ __launch_bounds__(256) void place_kernel_x(const int* __restrict__ src,
                                                      const int* __restrict__ dst,
                                                      int* __restrict__ cursor,
                                                      int* __restrict__ ssrc, int E, int ng) {
    int g = blockIdx.x & (XCDS - 1);
    int lo = g * ng, hi = lo + ng;
    int bid = blockIdx.x >> 3;
    int stride = (gridDim.x >> 3) * 256;
    for (int e = bid * 256 + threadIdx.x; e < E; e += stride) {
        int d = dst[e];
        if (d >= lo && d < hi) {
            int p = atomicAdd(&cursor[d], 1);
            ssrc[p] = src[e];
        }
    }
}

__global__ void scan_kernel(const int* __restrict__ cnt, int* __restrict__ offs, int n) {
    __shared__ int s[256];
    int carry = 0;
    if (threadIdx.x == 0) offs[0] = 0;
    for (int base = 0; base < n; base += 1024) {
        int i0 = base + threadIdx.x * 4;
        int v[4];
#pragma unroll
        for (int j = 0; j < 4; ++j) v[j] = (i0 + j < n) ? cnt[i0 + j] : 0;
        int lsum = v[0] + v[1] + v[2] + v[3];
        s[threadIdx.x] = lsum;
        __syncthreads();
        for (int off = 1; off < 256; off <<= 1) {
            int t = (threadIdx.x >= off) ? s[threadIdx.x - off] : 0;
            __syncthreads();
            s[threadIdx.x] += t;
            __syncthreads();
        }
        int run = s[threadIdx.x] - lsum + carry;
#pragma unroll
        for (int j = 0; j < 4; ++j) {
            run += v[j];
            if (i0 + j < n) offs[i0 + j + 1] = run;
        }
        carry += s[255];
        __syncthreads();
    }
}

__global__ void dinv_cursor_kernel(const int* __restrict__ cnt, const int* __restrict__ offs,
                                   float* __restrict__ dinv, int* __restrict__ cursor, int n) {
    int i = blockIdx.x * 256 + threadIdx.x;
    if (i < n) {
        dinv[i] = rsqrtf((float)(cnt[i] + 1));
        cursor[i] = offs[i];
    }
}

// ---------------- casts ----------------

// n must be a multiple of 2048 (12.8M = 2048*6250 OK)
__global__ __launch_bounds__(256) void cast_bf16_kernel(const float* __restrict__ in,
                                                        unsigned short* __restrict__ out, int n) {
    int i = (blockIdx.x * 256 + threadIdx.x) * 8;
    if (i >= n) return;
    float4 a = *(const float4*)&in[i];
    float4 b = *(const float4*)&in[i + 4];
    uint4 p;
    p.x = (unsigned)f2bf(a.x) | ((unsigned)f2bf(a.y) << 16);
    p.y = (unsigned)f2bf(a.z) | ((unsigned)f2bf(a.w) << 16);
    p.z = (unsigned)f2bf(b.x) | ((unsigned)f2bf(b.y) << 16);
    p.w = (unsigned)f2bf(b.z) | ((unsigned)f2bf(b.w) << 16);
    *(uint4*)&out[i] = p;
}

// Wt[n][k] = bf16(W[k][n]); grid = N blocks of 64 threads
__global__ void transpose_cast_kernel(const float* __restrict__ W,
                                      unsigned short* __restrict__ Wt, int K, int N) {
    int n = blockIdx.x;
    for (int k = threadIdx.x; k < K; k += 64)
        Wt[(size_t)n * K + k] = f2bf(W[(size_t)k * N + n]);
}

// ---------------- bf16 MFMA GEMM: C[M,N] = A[M,K] @ Bt[N,K]^T, bf16 out ----------------
// BM=128, BK=32, BN in {128,64}; 256 threads = 4 waves; wave w owns rows w*32..w*32+31.

template <int BN>
__global__ __launch_bounds__(256) void gemm_mfma_kernel(const unsigned short* __restrict__ A,
                                                        const unsigned short* __restrict__ Bt,
                                                        unsigned short* __restrict__ C,
                                                        int M, int K, int N) {
    constexpr int BM = 128, BK = 32, LDA = BK + 8;
    constexpr int CT = BN / 16;  // col tiles per wave
    __shared__ unsigned short As[BM][LDA];
    __shared__ unsigned short Bs[BN][LDA];
    int tid = threadIdx.x;
    int wave = tid >> 6, lane = tid & 63;
    int quad = lane >> 4, l16 = lane & 15;
    int row0 = blockIdx.x * BM, col0 = blockIdx.y * BN;

    f32x4 acc[2][CT];
#pragma unroll
    for (int i = 0; i < 2; ++i)
#pragma unroll
        for (int j = 0; j < CT; ++j) acc[i][j] = (f32x4){0.f, 0.f, 0.f, 0.f};

    int ar = tid >> 2;          // row within tile (0..63)
    int ac = (tid & 3) * 8;     // bf16 col offset (0,8,16,24)

    for (int k0 = 0; k0 < K; k0 += BK) {
#pragma unroll
        for (int i = 0; i < 2; ++i) {
            int r = ar + i * 64;
            int gr = row0 + r;
            uint4 v = make_uint4(0u, 0u, 0u, 0u);
            if (gr < M) v = *(const uint4*)&A[(size_t)gr * K + k0 + ac];
            *(uint4*)&As[r][ac] = v;
        }
#pragma unroll
        for (int i = 0; i < BN / 64; ++i) {
            int r = ar + i * 64;
            *(uint4*)&Bs[r][ac] = *(const uint4*)&Bt[(size_t)(col0 + r) * K + k0 + ac];
        }
        __syncthreads();
        bf16x8 af[2];
#pragma unroll
        for (int tr = 0; tr < 2; ++tr)
            af[tr] = *(const bf16x8*)&As[wave * 32 + tr * 16 + l16][quad * 8];
#pragma unroll
        for (int tc = 0; tc < CT; ++tc) {
            bf16x8 bf = *(const bf16x8*)&Bs[tc * 16 + l16][quad * 8];
            acc[0][tc] = __builtin_amdgcn_mfma_f32_16x16x32_bf16(af[0], bf, acc[0][tc], 0, 0, 0);
            acc[1][tc] = __builtin_amdgcn_mfma_f32_16x16x32_bf16(af[1], bf, acc[1][tc], 0, 0, 0);
        }
        __syncthreads();
    }
#pragma unroll
    for (int tr = 0; tr < 2; ++tr) {
        int gr0 = row0 + wave * 32 + tr * 16 + quad * 4;
#pragma unroll
        for (int tc = 0; tc < CT; ++tc) {
            int gc = col0 + tc * 16 + l16;
#pragma unroll
            for (int j = 0; j < 4; ++j) {
                int gr = gr0 + j;
                if (gr < M) C[(size_t)gr * N + gc] = f2bf(acc[tr][tc][j]);
            }
        }
    }
}

// ---------------- aggregation: one wave per node, bf16 gather ----------------

template <int F, bool RELU, typename OT>
__global__ __launch_bounds__(256) void agg_kernel(const unsigned short* __restrict__ h,
                                                  const float* __restrict__ dinv,
                                                  const int* __restrict__ offs,
                                                  const int* __restrict__ ssrc,
                                                  const float* __restrict__ bias,
                                                  OT* __restrict__ out, int N) {
    constexpr int V = F / 64;
    int n = blockIdx.x * 4 + (threadIdx.x >> 6);
    if (n >= N) return;
    int lane = threadIdx.x & 63;
    int c = lane * V;
    float di = dinv[n];
    float acc[V];

    auto loadrow = [&](int row, float w, float* a, bool init) {
        const unsigned short* p = h + (size_t)row * F + c;
        if constexpr (V == 4) {
            uint2 q = *(const uint2*)p;
            float f0 = __uint_as_float(q.x << 16);
            float f1 = __uint_as_float(q.x & 0xFFFF0000u);
            float f2 = __uint_as_float(q.y << 16);
            float f3 = __uint_as_float(q.y & 0xFFFF0000u);
            if (init) { a[0] = w * f0; a[1] = w * f1; a[2] = w * f2; a[3] = w * f3; }
            else { a[0] = fmaf(w, f0, a[0]); a[1] = fmaf(w, f1, a[1]);
                   a[2] = fmaf(w, f2, a[2]); a[3] = fmaf(w, f3, a[3]); }
        } else {
            unsigned q = *(const unsigned*)p;
            float f0 = __uint_as_float(q << 16);
            float f1 = __uint_as_float(q & 0xFFFF0000u);
            if (init) { a[0] = w * f0; a[1] = w * f1; }
            else { a[0] = fmaf(w, f0, a[0]); a[1] = fmaf(w, f1, a[1]); }
        }
    };

    loadrow(n, di, acc, true);

    int e = offs[n], e1 = offs[n + 1];
    for (; e + 4 <= e1; e += 4) {
        int s0 = ssrc[e + 0], s1 = ssrc[e + 1], s2 = ssrc[e + 2], s3 = ssrc[e + 3];
        float d0 = dinv[s0], d1 = dinv[s1], d2 = dinv[s2], d3 = dinv[s3];
        loadrow(s0, d0, acc, false);
        loadrow(s1, d1, acc, false);
        loadrow(s2, d2, acc, false);
        loadrow(s3, d3, acc, false);
    }
    for (; e < e1; ++e) {
        int s = ssrc[e];
        loadrow(s, dinv[s], acc, false);
    }

#pragma unroll
    for (int v = 0; v < V; ++v) {
        float r = fmaf(acc[v], di, bias[c + v]);
        if (RELU) r = fmaxf(r, 0.f);
        storev(&out[(size_t)n * F + c + v], r);
    }
}

// ---------------- launch ----------------

extern "C" void kernel_launch(void* const* d_in, const int* in_sizes, int n_in,
                              void* d_out, int out_size, void* d_ws, size_t ws_size,
                              hipStream_t stream) {
    const float* x  = (const float*)d_in[0];
    const int*   ei = (const int*)d_in[1];
    const float* W1 = (const float*)d_in[2];
    const float* b1 = (const float*)d_in[3];
    const float* W2 = (const float*)d_in[4];
    const float* b2 = (const float*)d_in[5];
    float* out = (float*)d_out;

    const int F0 = 256, F1 = 256, F2 = 128;
    const int N = in_sizes[0] / F0;   // 50000
    const int E = in_sizes[1] / 2;    // 1600000
    const int* src = ei;
    const int* dst = ei + E;
    const int ng = (N + XCDS - 1) / XCDS;

    char* ws = (char*)d_ws;
    size_t off = 0;
    auto alloc = [&](size_t bytes) {
        char* p = ws + off;
        off += (bytes + 255) & ~(size_t)255;
        return p;
    };
    int*            cnt    = (int*)alloc((size_t)N * 4);
    int*            offs   = (int*)alloc((size_t)(N + 1) * 4);
    int*            cursor = (int*)alloc((size_t)N * 4);
    float*          dinv   = (float*)alloc((size_t)N * 4);
    int*            ssrc   = (int*)alloc((size_t)E * 4);
    unsigned short* xb     = (unsigned short*)alloc((size_t)N * F0 * 2);  // bf16 x
    unsigned short* wt1    = (unsigned short*)alloc((size_t)F1 * F0 * 2); // bf16 W1^T
    unsigned short* wt2    = (unsigned short*)alloc((size_t)F2 * F1 * 2); // bf16 W2^T
    unsigned short* h1     = (unsigned short*)alloc((size_t)N * F1 * 2);  // bf16
    unsigned short* h1a    = (unsigned short*)alloc((size_t)N * F1 * 2);  // bf16
    unsigned short* h2     = (unsigned short*)alloc((size_t)N * F2 * 2);  // bf16
    (void)ws_size; (void)n_in; (void)out_size;

    // CSR build
    hipMemsetAsync(cnt, 0, (size_t)N * 4, stream);
    count_kernel_x<<<2048, 256, 0, stream>>>(dst, cnt, E, ng);
    scan_kernel<<<1, 256, 0, stream>>>(cnt, offs, N);
    dinv_cursor_kernel<<<(N + 255) / 256, 256, 0, stream>>>(cnt, offs, dinv, cursor, N);
    place_kernel_x<<<2048, 256, 0, stream>>>(src, dst, cursor, ssrc, E, ng);

    // casts
    cast_bf16_kernel<<<(N * F0) / 2048, 256, 0, stream>>>(x, xb, N * F0);
    transpose_cast_kernel<<<F1, 64, 0, stream>>>(W1, wt1, F0, F1);  // [256,256] -> [256][256]
    transpose_cast_kernel<<<F2, 64, 0, stream>>>(W2, wt2, F1, F2);  // [256,128] -> [128][256]

    // layer 1: h1 = xb @ W1 (MFMA), h1a = relu(agg(h1)) in bf16
    {
        dim3 grid((N + 127) / 128, F1 / 128);
        gemm_mfma_kernel<128><<<grid, 256, 0, stream>>>(xb, wt1, h1, N, F0, F1);
    }
    agg_kernel<256, true, unsigned short><<<(N + 3) / 4, 256, 0, stream>>>(
        h1, dinv, offs, ssrc, b1, h1a, N);

    // layer 2: h2 = h1a @ W2 (MFMA), out = agg(h2) + b2 in fp32
    {
        dim3 grid((N + 127) / 128, F2 / 64);
        gemm_mfma_kernel<64><<<grid, 256, 0, stream>>>(h1a, wt2, h2, N, F1, F2);
    }
    agg_kernel<128, false, float><<<(N + 3) / 4, 256, 0, stream>>>(
        h2, dinv, offs, ssrc, b2, out, N);
}